// Round 9
// baseline (328.455 us; speedup 1.0000x reference)
//
#include <hip/hip_runtime.h>
#include <hip/hip_bf16.h>
#include <math.h>
#include <limits.h>

typedef __attribute__((ext_vector_type(8))) short short8v;
typedef __attribute__((ext_vector_type(4))) float f32x4;

union U4 { uint4 u; short8v s; };

__device__ __forceinline__ uint32_t bf_hi_bits(float x) {
    uint32_t u = __float_as_uint(x);
    return (u + 0x7FFFu + ((u >> 16) & 1u)) >> 16;
}

// hw-convert split: returns (bf16_hi << 16) | bf16_lo
__device__ __forceinline__ uint32_t pack_split(float x) {
    __hip_bfloat16 h = __float2bfloat16(x);
    float fh = __bfloat162float(h);
    __hip_bfloat16 l = __float2bfloat16(x - fh);
    return ((uint32_t)__builtin_bit_cast(unsigned short, h) << 16)
         | (uint32_t)__builtin_bit_cast(unsigned short, l);
}

__device__ __forceinline__ float fast_tanh(float x) {
    float ax = fabsf(x);
    float e = __expf(2.0f * ax);
    float r = __builtin_amdgcn_rcpf(e + 1.0f);
    float t = fmaf(-2.0f, r, 1.0f);
    return copysignf(t, x);
}

__device__ __forceinline__ float Ffunc_f(float x, float y) {
    float e1 = __expf(-x * x - (y + 1.f) * (y + 1.f));
    float e2 = __expf(-x * x - y * y);
    float e3 = __expf(-(x + 1.f) * (x + 1.f) - y * y);
    float x3 = x * x * x;
    float y5 = y * y * y * y * y;
    return 3.f * (1.f - x) * (1.f - x) * e1
         - 10.f * (x * 0.2f - x3 - y5) * e2
         - __expf(-1.0986122886681098f * e3);
}

// Pack W1 (128x128) and W2 (128x64) into MFMA fragment order, bf16 hi/lo planes.
__global__ void pack_weights(const float* __restrict__ W1, const float* __restrict__ W2,
                             uint4* __restrict__ w1h, uint4* __restrict__ w1l,
                             uint4* __restrict__ w2h, uint4* __restrict__ w2l)
{
    const int b = blockIdx.x;
    const int tid = threadIdx.x;
    const int s = tid >> 6, lane = tid & 63, g = lane >> 4, c = lane & 15;
    const float* W; uint4 *oh, *ol; int t, ldw;
    if (b < 8) { W = W1; oh = w1h; ol = w1l; t = b;     ldw = 128; }
    else       { W = W2; oh = w2h; ol = w2l; t = b - 8; ldw = 64;  }
    const int n = 16 * t + c;
    uint32_t hb[8], lb[8];
    #pragma unroll
    for (int j = 0; j < 8; ++j) {
        int k = 32 * s + 8 * g + j;
        float v = W[k * ldw + n];
        uint32_t h = bf_hi_bits(v);
        float fh = __uint_as_float(h << 16);
        uint32_t l = bf_hi_bits(v - fh);
        hb[j] = h; lb[j] = l;
    }
    uint4 H = make_uint4(hb[0] | (hb[1] << 16), hb[2] | (hb[3] << 16),
                         hb[4] | (hb[5] << 16), hb[6] | (hb[7] << 16));
    uint4 L = make_uint4(lb[0] | (lb[1] << 16), lb[2] | (lb[3] << 16),
                         lb[4] | (lb[5] << 16), lb[6] | (lb[7] << 16));
    oh[(t * 4 + s) * 64 + lane] = H;
    ol[(t * 4 + s) * 64 + lane] = L;
}

#define MFMA __builtin_amdgcn_mfma_f32_16x16x32_bf16

// ONLY change vs R7: min-waves/EU 3 -> 6 (VGPR cap 84; kernel used 80 at bound 3).
// Isolated occupancy test: 12 -> 24 waves/CU.
__global__ __launch_bounds__(256, 6)
void fused_mlp(const int* __restrict__ data, const float* __restrict__ embed,
               const float* __restrict__ b1, const float* __restrict__ b2,
               const float* __restrict__ W3, const float* __restrict__ b3,
               const uint4* __restrict__ w1h, const uint4* __restrict__ w1l,
               const uint4* __restrict__ w2h, const uint4* __restrict__ w2l,
               float* __restrict__ wsF, float2* __restrict__ wsO,
               int* __restrict__ wsI, int N)
{
    __shared__ uint32_t embs_rep[48 * 32];   // bank-replicated packed embed (6 KB)
    __shared__ float b1s[128], W3s[128], b2s[64], b3s[2];
    __shared__ float candF[4];
    __shared__ int candI[4];
    __shared__ float2 candO[4];

    const int tid = threadIdx.x;
    const int w = tid >> 6, lane = tid & 63, g = lane >> 4, c = lane & 15;
    const int bank = lane & 31;
    const int base = blockIdx.x << 7;         // 128 rows per block (4 waves x 32 rows)

    // ---- issue BOTH row-fragments' data loads first (latency hides under table setup) ----
    const int row0 = base + 32 * w + c;       // fragment 0 rows: base+32w .. +15
    const size_t dr0 = (size_t)min(row0, N - 1) * 128;
    const size_t dr1 = (size_t)min(row0 + 16, N - 1) * 128;
    uint4 raw0[8], raw1[8];
    #pragma unroll
    for (int s = 0; s < 4; ++s) {
        const uint4* p0 = (const uint4*)&data[dr0 + 32 * s + 8 * g];
        raw0[2 * s] = p0[0]; raw0[2 * s + 1] = p0[1];
        const uint4* p1 = (const uint4*)&data[dr1 + 32 * s + 8 * g];
        raw1[2 * s] = p1[0]; raw1[2 * s + 1] = p1[1];
    }

    // bank-replicated packed embed: [idx][bank]; lane reads (idx<<5)+(lane&31) -> bank lane&31
    for (int u = tid; u < 48 * 32; u += 256) {
        float e = embed[u >> 5];
        uint32_t h = bf_hi_bits(e);
        float fh = __uint_as_float(h << 16);
        uint32_t l = bf_hi_bits(e - fh);
        embs_rep[u] = (h << 16) | l;
    }
    if (tid < 128) { b1s[tid] = b1[tid]; W3s[tid] = W3[tid]; }
    else if (tid < 192) b2s[tid - 128] = b2[tid - 128];
    if (tid < 2) b3s[tid] = b3[tid];
    __syncthreads();

    // ---- convert raw -> xh/xl fragments (conflict-free gather) ----
    uint4 xh0[4], xl0[4], xh1[4], xl1[4];
    #pragma unroll
    for (int s = 0; s < 4; ++s) {
        uint4 d0 = raw0[2 * s], d1 = raw0[2 * s + 1];
        uint32_t p0 = embs_rep[(d0.x << 5) + bank], p1 = embs_rep[(d0.y << 5) + bank];
        uint32_t p2 = embs_rep[(d0.z << 5) + bank], p3 = embs_rep[(d0.w << 5) + bank];
        uint32_t p4 = embs_rep[(d1.x << 5) + bank], p5 = embs_rep[(d1.y << 5) + bank];
        uint32_t p6 = embs_rep[(d1.z << 5) + bank], p7 = embs_rep[(d1.w << 5) + bank];
        xh0[s] = make_uint4((p1 & 0xFFFF0000u) | (p0 >> 16), (p3 & 0xFFFF0000u) | (p2 >> 16),
                            (p5 & 0xFFFF0000u) | (p4 >> 16), (p7 & 0xFFFF0000u) | (p6 >> 16));
        xl0[s] = make_uint4((p1 << 16) | (p0 & 0xFFFFu), (p3 << 16) | (p2 & 0xFFFFu),
                            (p5 << 16) | (p4 & 0xFFFFu), (p7 << 16) | (p6 & 0xFFFFu));
    }
    #pragma unroll
    for (int s = 0; s < 4; ++s) {
        uint4 d0 = raw1[2 * s], d1 = raw1[2 * s + 1];
        uint32_t p0 = embs_rep[(d0.x << 5) + bank], p1 = embs_rep[(d0.y << 5) + bank];
        uint32_t p2 = embs_rep[(d0.z << 5) + bank], p3 = embs_rep[(d0.w << 5) + bank];
        uint32_t p4 = embs_rep[(d1.x << 5) + bank], p5 = embs_rep[(d1.y << 5) + bank];
        uint32_t p6 = embs_rep[(d1.z << 5) + bank], p7 = embs_rep[(d1.w << 5) + bank];
        xh1[s] = make_uint4((p1 & 0xFFFF0000u) | (p0 >> 16), (p3 & 0xFFFF0000u) | (p2 >> 16),
                            (p5 & 0xFFFF0000u) | (p4 >> 16), (p7 & 0xFFFF0000u) | (p6 >> 16));
        xl1[s] = make_uint4((p1 << 16) | (p0 & 0xFFFFu), (p3 << 16) | (p2 & 0xFFFFu),
                            (p5 << 16) | (p4 & 0xFFFFu), (p7 << 16) | (p6 & 0xFFFFu));
    }

    const int src0 = ((g & 1) << 5) + c;
    const int src1 = src0 + 16;
    const int rsel = c >> 2;

    f32x4 acc2a[4], acc2b[4];
    #pragma unroll
    for (int t2 = 0; t2 < 4; ++t2) {
        float bv = b2s[16 * t2 + c];
        acc2a[t2] = (f32x4){bv, bv, bv, bv};
        acc2b[t2] = (f32x4){bv, bv, bv, bv};
    }

    // ---- fused layer1 (swapped operands, 2 row-frags share weight loads) -> shuffle -> layer2 ----
    #pragma unroll
    for (int s2 = 0; s2 < 4; ++s2) {
        f32x4 aA0, aB0, aA1, aB1;
        #pragma unroll
        for (int r = 0; r < 4; ++r) {
            float bvA = b1s[32 * s2 + 4 * g + r];
            float bvB = b1s[32 * s2 + 16 + 4 * g + r];
            aA0[r] = bvA; aA1[r] = bvA;
            aB0[r] = bvB; aB1[r] = bvB;
        }
        #pragma unroll
        for (int s = 0; s < 4; ++s) {
            U4 bh0, bl0, bh1, bl1, ah, al;
            bh0.u = w1h[(8 * s2 + s) * 64 + lane];
            bl0.u = w1l[(8 * s2 + s) * 64 + lane];
            bh1.u = w1h[(8 * s2 + 4 + s) * 64 + lane];
            bl1.u = w1l[(8 * s2 + 4 + s) * 64 + lane];
            ah.u = xh0[s]; al.u = xl0[s];
            aA0 = MFMA(bh0.s, ah.s, aA0, 0, 0, 0);
            aA0 = MFMA(bh0.s, al.s, aA0, 0, 0, 0);
            aA0 = MFMA(bl0.s, ah.s, aA0, 0, 0, 0);
            aB0 = MFMA(bh1.s, ah.s, aB0, 0, 0, 0);
            aB0 = MFMA(bh1.s, al.s, aB0, 0, 0, 0);
            aB0 = MFMA(bl1.s, ah.s, aB0, 0, 0, 0);
            ah.u = xh1[s]; al.u = xl1[s];
            aA1 = MFMA(bh0.s, ah.s, aA1, 0, 0, 0);
            aA1 = MFMA(bh0.s, al.s, aA1, 0, 0, 0);
            aA1 = MFMA(bl0.s, ah.s, aA1, 0, 0, 0);
            aB1 = MFMA(bh1.s, ah.s, aB1, 0, 0, 0);
            aB1 = MFMA(bh1.s, al.s, aB1, 0, 0, 0);
            aB1 = MFMA(bl1.s, ah.s, aB1, 0, 0, 0);
        }
        // relu + split + pack + quad redistribution, per fragment
        uint32_t pA[4], pB[4], q0[4], q1[4];
        U4 ah2_0, al2_0, ah2_1, al2_1;
        #pragma unroll
        for (int r = 0; r < 4; ++r) {
            pA[r] = pack_split(fmaxf(aA0[r], 0.f));
            pB[r] = pack_split(fmaxf(aB0[r], 0.f));
        }
        #pragma unroll
        for (int r = 0; r < 4; ++r) {
            uint32_t a0v = __shfl(pA[r], src0, 64);
            uint32_t b0v = __shfl(pB[r], src0, 64);
            uint32_t a1v = __shfl(pA[r], src1, 64);
            uint32_t b1v = __shfl(pB[r], src1, 64);
            q0[r] = (lane < 32) ? a0v : b0v;
            q1[r] = (lane < 32) ? a1v : b1v;
        }
        ah2_0.u = make_uint4((q0[1] & 0xFFFF0000u) | (q0[0] >> 16),
                             (q0[3] & 0xFFFF0000u) | (q0[2] >> 16),
                             (q1[1] & 0xFFFF0000u) | (q1[0] >> 16),
                             (q1[3] & 0xFFFF0000u) | (q1[2] >> 16));
        al2_0.u = make_uint4((q0[1] << 16) | (q0[0] & 0xFFFFu),
                             (q0[3] << 16) | (q0[2] & 0xFFFFu),
                             (q1[1] << 16) | (q1[0] & 0xFFFFu),
                             (q1[3] << 16) | (q1[2] & 0xFFFFu));
        #pragma unroll
        for (int r = 0; r < 4; ++r) {
            pA[r] = pack_split(fmaxf(aA1[r], 0.f));
            pB[r] = pack_split(fmaxf(aB1[r], 0.f));
        }
        #pragma unroll
        for (int r = 0; r < 4; ++r) {
            uint32_t a0v = __shfl(pA[r], src0, 64);
            uint32_t b0v = __shfl(pB[r], src0, 64);
            uint32_t a1v = __shfl(pA[r], src1, 64);
            uint32_t b1v = __shfl(pB[r], src1, 64);
            q0[r] = (lane < 32) ? a0v : b0v;
            q1[r] = (lane < 32) ? a1v : b1v;
        }
        ah2_1.u = make_uint4((q0[1] & 0xFFFF0000u) | (q0[0] >> 16),
                             (q0[3] & 0xFFFF0000u) | (q0[2] >> 16),
                             (q1[1] & 0xFFFF0000u) | (q1[0] >> 16),
                             (q1[3] & 0xFFFF0000u) | (q1[2] >> 16));
        al2_1.u = make_uint4((q0[1] << 16) | (q0[0] & 0xFFFFu),
                             (q0[3] << 16) | (q0[2] & 0xFFFFu),
                             (q1[1] << 16) | (q1[0] & 0xFFFFu),
                             (q1[3] << 16) | (q1[2] & 0xFFFFu));
        // layer-2 k-slice s2, shared W2 fragment loads
        #pragma unroll
        for (int t2 = 0; t2 < 4; ++t2) {
            U4 b2h, b2l;
            b2h.u = w2h[(t2 * 4 + s2) * 64 + lane];
            b2l.u = w2l[(t2 * 4 + s2) * 64 + lane];
            acc2a[t2] = MFMA(ah2_0.s, b2h.s, acc2a[t2], 0, 0, 0);
            acc2a[t2] = MFMA(al2_0.s, b2h.s, acc2a[t2], 0, 0, 0);
            acc2a[t2] = MFMA(ah2_0.s, b2l.s, acc2a[t2], 0, 0, 0);
            acc2b[t2] = MFMA(ah2_1.s, b2h.s, acc2b[t2], 0, 0, 0);
            acc2b[t2] = MFMA(al2_1.s, b2h.s, acc2b[t2], 0, 0, 0);
            acc2b[t2] = MFMA(ah2_1.s, b2l.s, acc2b[t2], 0, 0, 0);
        }
    }

    // ---- tanh + layer-3 partials, per fragment ----
    float bestF = -INFINITY; int bestI = INT_MAX; float bo0 = 0.f, bo1 = 0.f;
    #pragma unroll
    for (int f = 0; f < 2; ++f) {
        float po0[4] = {0.f, 0.f, 0.f, 0.f};
        float po1[4] = {0.f, 0.f, 0.f, 0.f};
        #pragma unroll
        for (int t2 = 0; t2 < 4; ++t2) {
            int col = 16 * t2 + c;
            float w30 = W3s[2 * col], w31 = W3s[2 * col + 1];
            f32x4 accv = (f == 0) ? acc2a[t2] : acc2b[t2];
            #pragma unroll
            for (int r = 0; r < 4; ++r) {
                float h = fast_tanh(accv[r]);
                po0[r] = fmaf(h, w30, po0[r]);
                po1[r] = fmaf(h, w31, po1[r]);
            }
        }
        #pragma unroll
        for (int r = 0; r < 4; ++r) {
            po0[r] += __shfl_xor(po0[r], 4, 64);
            po0[r] += __shfl_xor(po0[r], 8, 64);
            po1[r] += __shfl_xor(po1[r], 4, 64);
            po1[r] += __shfl_xor(po1[r], 8, 64);
        }
        float v0 = (rsel == 0) ? po0[0] : (rsel == 1) ? po0[1] : (rsel == 2) ? po0[2] : po0[3];
        float v1 = (rsel == 0) ? po1[0] : (rsel == 1) ? po1[1] : (rsel == 2) ? po1[2] : po1[3];
        v0 += __shfl_xor(v0, 1, 64); v0 += __shfl_xor(v0, 2, 64);
        v1 += __shfl_xor(v1, 1, 64); v1 += __shfl_xor(v1, 2, 64);

        const int row = base + 32 * w + 16 * f + 4 * g + rsel;
        if (row < N) {
            float o0 = v0 + b3s[0], o1 = v1 + b3s[1];
            float Fv = Ffunc_f(o0, o1);
            // row strictly increases with f -> '>' keeps first index on ties
            if (Fv > bestF) { bestF = Fv; bestI = row; bo0 = o0; bo1 = o1; }
        }
    }

    // ---- 64-lane argmax (first-index tie-break) ----
    #pragma unroll
    for (int m = 32; m > 0; m >>= 1) {
        float Fo = __shfl_xor(bestF, m, 64);
        int io   = __shfl_xor(bestI, m, 64);
        float c0 = __shfl_xor(bo0, m, 64);
        float c1 = __shfl_xor(bo1, m, 64);
        if (Fo > bestF || (Fo == bestF && io < bestI)) {
            bestF = Fo; bestI = io; bo0 = c0; bo1 = c1;
        }
    }
    if (lane == 0) { candF[w] = bestF; candI[w] = bestI; candO[w] = make_float2(bo0, bo1); }
    __syncthreads();
    if (tid == 0) {
        float bF = candF[0]; int bI = candI[0]; float2 bO = candO[0];
        #pragma unroll
        for (int u = 1; u < 4; ++u) {
            if (candF[u] > bF || (candF[u] == bF && candI[u] < bI)) {
                bF = candF[u]; bI = candI[u]; bO = candO[u];
            }
        }
        wsF[blockIdx.x] = bF; wsI[blockIdx.x] = bI; wsO[blockIdx.x] = bO;
    }
}

__global__ __launch_bounds__(256, 1)
void reduce_cands(const float* __restrict__ wsF, const float2* __restrict__ wsO,
                  const int* __restrict__ wsI, int nB, float* __restrict__ out)
{
    __shared__ float sF[4];
    __shared__ int sI[4];
    __shared__ float2 sO[4];
    const int tid = threadIdx.x;
    const int w = tid >> 6, lane = tid & 63;
    float Fv = -INFINITY; int idx = INT_MAX; float2 o = make_float2(0.f, 0.f);
    for (int u = tid; u < nB; u += 256) {
        float f = wsF[u]; int i = wsI[u];
        if (f > Fv || (f == Fv && i < idx)) { Fv = f; idx = i; o = wsO[u]; }
    }
    #pragma unroll
    for (int m = 32; m > 0; m >>= 1) {
        float Fo = __shfl_xor(Fv, m, 64);
        int io   = __shfl_xor(idx, m, 64);
        float c0 = __shfl_xor(o.x, m, 64);
        float c1 = __shfl_xor(o.y, m, 64);
        if (Fo > Fv || (Fo == Fv && io < idx)) { Fv = Fo; idx = io; o = make_float2(c0, c1); }
    }
    if (lane == 0) { sF[w] = Fv; sI[w] = idx; sO[w] = o; }
    __syncthreads();
    if (tid == 0) {
        float bF = sF[0]; int bI = sI[0]; float2 bO = sO[0];
        #pragma unroll
        for (int u = 1; u < 4; ++u) {
            if (sF[u] > bF || (sF[u] == bF && sI[u] < bI)) { bF = sF[u]; bI = sI[u]; bO = sO[u]; }
        }
        out[0] = bO.x;
        out[1] = bO.y;
    }
}

extern "C" void kernel_launch(void* const* d_in, const int* in_sizes, int n_in,
                              void* d_out, int out_size, void* d_ws, size_t ws_size,
                              hipStream_t stream) {
    const int*   data  = (const int*)d_in[0];
    const float* embed = (const float*)d_in[1];
    const float* W1    = (const float*)d_in[2];
    const float* b1    = (const float*)d_in[3];
    const float* W2    = (const float*)d_in[4];
    const float* b2    = (const float*)d_in[5];
    const float* W3    = (const float*)d_in[6];
    const float* b3    = (const float*)d_in[7];

    const int N = in_sizes[0] / 128;
    const int nB = (N + 127) >> 7;              // 128 rows per block

    char* ws = (char*)d_ws;
    uint4* w1h = (uint4*)ws;            // contiguous 96 KB packed-weight block
    uint4* w1l = w1h + 2048;
    uint4* w2h = w1l + 2048;
    uint4* w2l = w2h + 1024;
    char* ws2 = ws + 98304;
    float2* wsO = (float2*)ws2;
    float*  wsF = (float*)(ws2 + (size_t)nB * 8);
    int*    wsI = (int*)(ws2 + (size_t)nB * 12);

    pack_weights<<<12, 256, 0, stream>>>(W1, W2, w1h, w1l, w2h, w2l);
    fused_mlp<<<nB, 256, 0, stream>>>(data, embed, b1, b2, W3, b3,
                                      w1h, w1l, w2h, w2l, wsF, wsO, wsI, N);
    reduce_cands<<<1, 256, 0, stream>>>(wsF, wsO, wsI, nB, (float*)d_out);
}

// Round 10
// 135.823 us; speedup vs baseline: 2.4183x; 2.4183x over previous
//
#include <hip/hip_runtime.h>
#include <hip/hip_bf16.h>
#include <math.h>
#include <limits.h>

typedef __attribute__((ext_vector_type(8))) short short8v;
typedef __attribute__((ext_vector_type(4))) float f32x4;

union U4 { uint4 u; short8v s; };

__device__ __forceinline__ uint32_t bf_hi_bits(float x) {
    uint32_t u = __float_as_uint(x);
    return (u + 0x7FFFu + ((u >> 16) & 1u)) >> 16;
}

// hw-convert split: returns (bf16_hi << 16) | bf16_lo
__device__ __forceinline__ uint32_t pack_split(float x) {
    __hip_bfloat16 h = __float2bfloat16(x);
    float fh = __bfloat162float(h);
    __hip_bfloat16 l = __float2bfloat16(x - fh);
    return ((uint32_t)__builtin_bit_cast(unsigned short, h) << 16)
         | (uint32_t)__builtin_bit_cast(unsigned short, l);
}

__device__ __forceinline__ float fast_tanh(float x) {
    float ax = fabsf(x);
    float e = __expf(2.0f * ax);
    float r = __builtin_amdgcn_rcpf(e + 1.0f);
    float t = fmaf(-2.0f, r, 1.0f);
    return copysignf(t, x);
}

__device__ __forceinline__ float Ffunc_f(float x, float y) {
    float e1 = __expf(-x * x - (y + 1.f) * (y + 1.f));
    float e2 = __expf(-x * x - y * y);
    float e3 = __expf(-(x + 1.f) * (x + 1.f) - y * y);
    float x3 = x * x * x;
    float y5 = y * y * y * y * y;
    return 3.f * (1.f - x) * (1.f - x) * e1
         - 10.f * (x * 0.2f - x3 - y5) * e2
         - __expf(-1.0986122886681098f * e3);
}

// Pack W1 (128x128) and W2 (128x64) into MFMA fragment order, bf16 hi/lo planes.
// d_ws layout CONTIGUOUS: w1h (2048 uint4) | w1l (2048) | w2h (1024) | w2l (1024).
__global__ void pack_weights(const float* __restrict__ W1, const float* __restrict__ W2,
                             uint4* __restrict__ w1h, uint4* __restrict__ w1l,
                             uint4* __restrict__ w2h, uint4* __restrict__ w2l)
{
    const int b = blockIdx.x;
    const int tid = threadIdx.x;
    const int s = tid >> 6, lane = tid & 63, g = lane >> 4, c = lane & 15;
    const float* W; uint4 *oh, *ol; int t, ldw;
    if (b < 8) { W = W1; oh = w1h; ol = w1l; t = b;     ldw = 128; }
    else       { W = W2; oh = w2h; ol = w2l; t = b - 8; ldw = 64;  }
    const int n = 16 * t + c;
    uint32_t hb[8], lb[8];
    #pragma unroll
    for (int j = 0; j < 8; ++j) {
        int k = 32 * s + 8 * g + j;
        float v = W[k * ldw + n];
        uint32_t h = bf_hi_bits(v);
        float fh = __uint_as_float(h << 16);
        uint32_t l = bf_hi_bits(v - fh);
        hb[j] = h; lb[j] = l;
    }
    uint4 H = make_uint4(hb[0] | (hb[1] << 16), hb[2] | (hb[3] << 16),
                         hb[4] | (hb[5] << 16), hb[6] | (hb[7] << 16));
    uint4 L = make_uint4(lb[0] | (lb[1] << 16), lb[2] | (lb[3] << 16),
                         lb[4] | (lb[5] << 16), lb[6] | (lb[7] << 16));
    oh[(t * 4 + s) * 64 + lane] = H;
    ol[(t * 4 + s) * 64 + lane] = L;
}

#define MFMA __builtin_amdgcn_mfma_f32_16x16x32_bf16

#define TPB 512
#define NWAVE 8

// LDS offsets (uint4 units): W1 hi at 0, W1 lo at 2048
#define OFF_W1H 0
#define OFF_W1L 2048

__global__ __launch_bounds__(TPB, 4)
void fused_mlp(const int* __restrict__ data, const float* __restrict__ embed,
               const float* __restrict__ b1, const float* __restrict__ b2,
               const float* __restrict__ W3, const float* __restrict__ b3,
               const uint4* __restrict__ wpack,   // first 4096 uint4 = W1 hi|lo
               const uint4* __restrict__ w2h, const uint4* __restrict__ w2l,
               float* __restrict__ wsF, float2* __restrict__ wsO,
               int* __restrict__ wsI, int N)
{
    __shared__ __align__(16) uint4 w1lds[4096];     // 64 KB W1 fragments (hi|lo)
    __shared__ uint32_t embs_rep[48 * 32];          // bank-replicated packed embed (6 KB)
    __shared__ float b1s[128], W3s[128], b2s[64], b3s[2];
    __shared__ float candF[NWAVE];
    __shared__ int candI[NWAVE];
    __shared__ float2 candO[NWAVE];

    const int tid = threadIdx.x;
    const int w = tid >> 6, lane = tid & 63, g = lane >> 4, c = lane & 15;
    const int bank = lane & 31;
    const int base = blockIdx.x << 7;         // 128 rows per block (8 waves x 16 rows)

    // ---- issue this wave's data loads first (latency hides under staging) ----
    const int row0 = base + 16 * w + c;
    const size_t dr0 = (size_t)min(row0, N - 1) * 128;
    uint4 raw0[8];
    #pragma unroll
    for (int s = 0; s < 4; ++s) {
        const uint4* p0 = (const uint4*)&data[dr0 + 32 * s + 8 * g];
        raw0[2 * s] = p0[0]; raw0[2 * s + 1] = p0[1];
    }

    // bank-replicated packed embed: [idx][bank]
    for (int u = tid; u < 48 * 32; u += TPB) {
        float e = embed[u >> 5];
        uint32_t h = bf_hi_bits(e);
        float fh = __uint_as_float(h << 16);
        uint32_t l = bf_hi_bits(e - fh);
        embs_rep[u] = (h << 16) | l;
    }
    if (tid < 128) { b1s[tid] = b1[tid]; W3s[tid] = W3[tid]; }
    else if (tid < 192) b2s[tid - 128] = b2[tid - 128];
    if (tid < 2) b3s[tid] = b3[tid];

    // stage W1 fragments (64 KB contiguous in global)
    #pragma unroll
    for (int u = 0; u < 8; ++u)
        w1lds[u * TPB + tid] = wpack[u * TPB + tid];
    __syncthreads();

    // ---- convert raw -> xh/xl fragments (conflict-free gather) ----
    uint4 xh0[4], xl0[4];
    #pragma unroll
    for (int s = 0; s < 4; ++s) {
        uint4 d0 = raw0[2 * s], d1 = raw0[2 * s + 1];
        uint32_t p0 = embs_rep[(d0.x << 5) + bank], p1 = embs_rep[(d0.y << 5) + bank];
        uint32_t p2 = embs_rep[(d0.z << 5) + bank], p3 = embs_rep[(d0.w << 5) + bank];
        uint32_t p4 = embs_rep[(d1.x << 5) + bank], p5 = embs_rep[(d1.y << 5) + bank];
        uint32_t p6 = embs_rep[(d1.z << 5) + bank], p7 = embs_rep[(d1.w << 5) + bank];
        xh0[s] = make_uint4((p1 & 0xFFFF0000u) | (p0 >> 16), (p3 & 0xFFFF0000u) | (p2 >> 16),
                            (p5 & 0xFFFF0000u) | (p4 >> 16), (p7 & 0xFFFF0000u) | (p6 >> 16));
        xl0[s] = make_uint4((p1 << 16) | (p0 & 0xFFFFu), (p3 << 16) | (p2 & 0xFFFFu),
                            (p5 << 16) | (p4 & 0xFFFFu), (p7 << 16) | (p6 & 0xFFFFu));
    }

    const int src0 = ((g & 1) << 5) + c;
    const int src1 = src0 + 16;
    const int rsel = c >> 2;

    f32x4 acc2[4];
    #pragma unroll
    for (int t2 = 0; t2 < 4; ++t2) {
        float bv = b2s[16 * t2 + c];
        acc2[t2] = (f32x4){bv, bv, bv, bv};
    }

    // ---- fused layer1 (swapped operands; W1 from LDS) -> shuffle -> layer2 (W2 from L2) ----
    #pragma unroll
    for (int s2 = 0; s2 < 4; ++s2) {
        f32x4 aA, aB;
        #pragma unroll
        for (int r = 0; r < 4; ++r) {
            aA[r] = b1s[32 * s2 + 4 * g + r];
            aB[r] = b1s[32 * s2 + 16 + 4 * g + r];
        }
        #pragma unroll
        for (int s = 0; s < 4; ++s) {
            U4 bh0, bl0, bh1, bl1, ah, al;
            bh0.u = w1lds[OFF_W1H + (8 * s2 + s) * 64 + lane];
            bl0.u = w1lds[OFF_W1L + (8 * s2 + s) * 64 + lane];
            bh1.u = w1lds[OFF_W1H + (8 * s2 + 4 + s) * 64 + lane];
            bl1.u = w1lds[OFF_W1L + (8 * s2 + 4 + s) * 64 + lane];
            ah.u = xh0[s]; al.u = xl0[s];
            aA = MFMA(bh0.s, ah.s, aA, 0, 0, 0);
            aA = MFMA(bh0.s, al.s, aA, 0, 0, 0);
            aA = MFMA(bl0.s, ah.s, aA, 0, 0, 0);
            aB = MFMA(bh1.s, ah.s, aB, 0, 0, 0);
            aB = MFMA(bh1.s, al.s, aB, 0, 0, 0);
            aB = MFMA(bl1.s, ah.s, aB, 0, 0, 0);
        }
        // relu + split + pack + quad redistribution
        uint32_t pA[4], pB[4], q0[4], q1[4];
        #pragma unroll
        for (int r = 0; r < 4; ++r) {
            pA[r] = pack_split(fmaxf(aA[r], 0.f));
            pB[r] = pack_split(fmaxf(aB[r], 0.f));
        }
        #pragma unroll
        for (int r = 0; r < 4; ++r) {
            uint32_t a0v = __shfl(pA[r], src0, 64);
            uint32_t b0v = __shfl(pB[r], src0, 64);
            uint32_t a1v = __shfl(pA[r], src1, 64);
            uint32_t b1v = __shfl(pB[r], src1, 64);
            q0[r] = (lane < 32) ? a0v : b0v;
            q1[r] = (lane < 32) ? a1v : b1v;
        }
        U4 ah2, al2;
        ah2.u = make_uint4((q0[1] & 0xFFFF0000u) | (q0[0] >> 16),
                           (q0[3] & 0xFFFF0000u) | (q0[2] >> 16),
                           (q1[1] & 0xFFFF0000u) | (q1[0] >> 16),
                           (q1[3] & 0xFFFF0000u) | (q1[2] >> 16));
        al2.u = make_uint4((q0[1] << 16) | (q0[0] & 0xFFFFu),
                           (q0[3] << 16) | (q0[2] & 0xFFFFu),
                           (q1[1] << 16) | (q1[0] & 0xFFFFu),
                           (q1[3] << 16) | (q1[2] & 0xFFFFu));
        // layer-2 k-slice s2
        #pragma unroll
        for (int t2 = 0; t2 < 4; ++t2) {
            U4 b2hv, b2lv;
            b2hv.u = w2h[(t2 * 4 + s2) * 64 + lane];
            b2lv.u = w2l[(t2 * 4 + s2) * 64 + lane];
            acc2[t2] = MFMA(ah2.s, b2hv.s, acc2[t2], 0, 0, 0);
            acc2[t2] = MFMA(al2.s, b2hv.s, acc2[t2], 0, 0, 0);
            acc2[t2] = MFMA(ah2.s, b2lv.s, acc2[t2], 0, 0, 0);
        }
    }

    // ---- tanh + layer-3 partials in-register ----
    float po0[4] = {0.f, 0.f, 0.f, 0.f};
    float po1[4] = {0.f, 0.f, 0.f, 0.f};
    #pragma unroll
    for (int t2 = 0; t2 < 4; ++t2) {
        int col = 16 * t2 + c;
        float w30 = W3s[2 * col], w31 = W3s[2 * col + 1];
        #pragma unroll
        for (int r = 0; r < 4; ++r) {
            float h = fast_tanh(acc2[t2][r]);
            po0[r] = fmaf(h, w30, po0[r]);
            po1[r] = fmaf(h, w31, po1[r]);
        }
    }
    #pragma unroll
    for (int r = 0; r < 4; ++r) {
        po0[r] += __shfl_xor(po0[r], 4, 64);
        po0[r] += __shfl_xor(po0[r], 8, 64);
        po1[r] += __shfl_xor(po1[r], 4, 64);
        po1[r] += __shfl_xor(po1[r], 8, 64);
    }
    float v0 = (rsel == 0) ? po0[0] : (rsel == 1) ? po0[1] : (rsel == 2) ? po0[2] : po0[3];
    float v1 = (rsel == 0) ? po1[0] : (rsel == 1) ? po1[1] : (rsel == 2) ? po1[2] : po1[3];
    v0 += __shfl_xor(v0, 1, 64); v0 += __shfl_xor(v0, 2, 64);
    v1 += __shfl_xor(v1, 1, 64); v1 += __shfl_xor(v1, 2, 64);

    const int row = base + 16 * w + 4 * g + rsel;
    float o0 = v0 + b3s[0], o1 = v1 + b3s[1];
    float bestF = -INFINITY; int bestI = INT_MAX;
    if (row < N) { bestF = Ffunc_f(o0, o1); bestI = row; }

    // ---- 64-lane argmax (first-index tie-break) ----
    #pragma unroll
    for (int m = 32; m > 0; m >>= 1) {
        float Fo = __shfl_xor(bestF, m, 64);
        int io   = __shfl_xor(bestI, m, 64);
        float c0 = __shfl_xor(o0, m, 64);
        float c1 = __shfl_xor(o1, m, 64);
        if (Fo > bestF || (Fo == bestF && io < bestI)) {
            bestF = Fo; bestI = io; o0 = c0; o1 = c1;
        }
    }
    if (lane == 0) { candF[w] = bestF; candI[w] = bestI; candO[w] = make_float2(o0, o1); }
    __syncthreads();
    if (tid == 0) {
        float bF = candF[0]; int bI = candI[0]; float2 bO = candO[0];
        #pragma unroll
        for (int u = 1; u < NWAVE; ++u) {
            if (candF[u] > bF || (candF[u] == bF && candI[u] < bI)) {
                bF = candF[u]; bI = candI[u]; bO = candO[u];
            }
        }
        wsF[blockIdx.x] = bF; wsI[blockIdx.x] = bI; wsO[blockIdx.x] = bO;
    }
}

__global__ __launch_bounds__(256, 1)
void reduce_cands(const float* __restrict__ wsF, const float2* __restrict__ wsO,
                  const int* __restrict__ wsI, int nB, float* __restrict__ out)
{
    __shared__ float sF[4];
    __shared__ int sI[4];
    __shared__ float2 sO[4];
    const int tid = threadIdx.x;
    const int w = tid >> 6, lane = tid & 63;
    float Fv = -INFINITY; int idx = INT_MAX; float2 o = make_float2(0.f, 0.f);
    for (int u = tid; u < nB; u += 256) {
        float f = wsF[u]; int i = wsI[u];
        if (f > Fv || (f == Fv && i < idx)) { Fv = f; idx = i; o = wsO[u]; }
    }
    #pragma unroll
    for (int m = 32; m > 0; m >>= 1) {
        float Fo = __shfl_xor(Fv, m, 64);
        int io   = __shfl_xor(idx, m, 64);
        float c0 = __shfl_xor(o.x, m, 64);
        float c1 = __shfl_xor(o.y, m, 64);
        if (Fo > Fv || (Fo == Fv && io < idx)) { Fv = Fo; idx = io; o = make_float2(c0, c1); }
    }
    if (lane == 0) { sF[w] = Fv; sI[w] = idx; sO[w] = o; }
    __syncthreads();
    if (tid == 0) {
        float bF = sF[0]; int bI = sI[0]; float2 bO = sO[0];
        #pragma unroll
        for (int u = 1; u < 4; ++u) {
            if (sF[u] > bF || (sF[u] == bF && sI[u] < bI)) { bF = sF[u]; bI = sI[u]; bO = sO[u]; }
        }
        out[0] = bO.x;
        out[1] = bO.y;
    }
}

extern "C" void kernel_launch(void* const* d_in, const int* in_sizes, int n_in,
                              void* d_out, int out_size, void* d_ws, size_t ws_size,
                              hipStream_t stream) {
    const int*   data  = (const int*)d_in[0];
    const float* embed = (const float*)d_in[1];
    const float* W1    = (const float*)d_in[2];
    const float* b1    = (const float*)d_in[3];
    const float* W2    = (const float*)d_in[4];
    const float* b2    = (const float*)d_in[5];
    const float* W3    = (const float*)d_in[6];
    const float* b3    = (const float*)d_in[7];

    const int N = in_sizes[0] / 128;
    const int nB = (N + 127) >> 7;              // 128 rows per block

    char* ws = (char*)d_ws;
    uint4* w1h = (uint4*)ws;            // contiguous: w1h|w1l = first 64 KB (staged to LDS)
    uint4* w1l = w1h + 2048;
    uint4* w2h = w1l + 2048;            // W2 stays in global (L2-served)
    uint4* w2l = w2h + 1024;
    char* ws2 = ws + 98304;
    float2* wsO = (float2*)ws2;
    float*  wsF = (float*)(ws2 + (size_t)nB * 8);
    int*    wsI = (int*)(ws2 + (size_t)nB * 12);

    pack_weights<<<12, 256, 0, stream>>>(W1, W2, w1h, w1l, w2h, w2l);
    fused_mlp<<<nB, TPB, 0, stream>>>(data, embed, b1, b2, W3, b3,
                                      (const uint4*)ws, w2h, w2l, wsF, wsO, wsI, N);
    reduce_cands<<<1, 256, 0, stream>>>(wsF, wsO, wsI, nB, (float*)d_out);
}